// Round 6
// baseline (131.890 us; speedup 1.0000x reference)
//
#include <hip/hip_runtime.h>
#include <hip/hip_bf16.h>
#include <stdint.h>

#define NB 4
#define NQL 1024
#define NL 2048
#define NH 16
#define NKVH 4
#define ND 128
#define KVBLK 32
// (1/sqrt(128)) * log2(e): scores land in log2 domain, softmax uses exp2
#define QSCALE_LOG2E 0.1275174340213733f

typedef __bf16 bf16_t;
typedef __bf16 bf16x4 __attribute__((ext_vector_type(4)));
typedef __bf16 bf16x8 __attribute__((ext_vector_type(8)));
typedef float f32x4 __attribute__((ext_vector_type(4)));
typedef uint32_t u32;
typedef unsigned short u16;

__device__ __forceinline__ void gload_lds16(const void* g, void* l) {
  __builtin_amdgcn_global_load_lds((const __attribute__((address_space(1))) void*)g,
                                   (__attribute__((address_space(3))) void*)l,
                                   16, 0, 0);
}

__device__ __forceinline__ u32 pack_bf16(float a, float b) {
  u32 ua = (u32)__builtin_bit_cast(u16, (bf16_t)a);
  u32 ub = (u32)__builtin_bit_cast(u16, (bf16_t)b);
  return ua | (ub << 16);
}

// ---------------------------------------------------------------------------
// Kernel 1: scatter new k/v into caches -> f32 outputs; also bf16 K copy to ws.
// ---------------------------------------------------------------------------
__global__ __launch_bounds__(256) void update_cache_kernel(
    const float* __restrict__ knew,
    const float* __restrict__ vnew,
    const float* __restrict__ cache_k,
    const float* __restrict__ cache_v,
    const int*   __restrict__ seq_lens,
    float* __restrict__ new_ck,
    float* __restrict__ new_cv,
    bf16_t* __restrict__ kb)
{
  const int n4 = NB * NKVH * NL * ND / 4;
  for (int i = blockIdx.x * blockDim.x + threadIdx.x; i < 2 * n4;
       i += gridDim.x * blockDim.x) {
    const int which = i >= n4;
    const int j   = which ? i - n4 : i;
    const int d4  = j & 31;
    const int l   = (j >> 5) & (NL - 1);
    const int kvh = (j >> 16) & (NKVH - 1);
    const int b   = j >> 18;
    const int s   = seq_lens[b];
    float4 val;
    if (l >= s && l < s + NQL) {
      const float* nsrc = which ? vnew : knew;
      val = *(const float4*)(nsrc + (((size_t)(b * NQL + (l - s))) * NKVH + kvh) * ND + d4 * 4);
    } else {
      const float* csrc = which ? cache_v : cache_k;
      val = *(const float4*)(csrc + (((size_t)(b * NKVH + kvh)) * NL + l) * ND + d4 * 4);
    }
    const size_t coff = (((size_t)(b * NKVH + kvh)) * NL + l) * ND + d4 * 4;
    float* dst = which ? new_cv : new_ck;
    *(float4*)(dst + coff) = val;
    if (!which) {
      bf16x4 kv;
      kv[0] = (bf16_t)val.x; kv[1] = (bf16_t)val.y;
      kv[2] = (bf16_t)val.z; kv[3] = (bf16_t)val.w;
      *(bf16x4*)(kb + coff) = kv;
    }
  }
}

// ---------------------------------------------------------------------------
// Kernel 2: build bf16 V^T [B][KVH][D][L] from updated f32 V cache.
// ---------------------------------------------------------------------------
__global__ __launch_bounds__(256) void transpose_v_kernel(
    const float* __restrict__ new_cv, bf16_t* __restrict__ vt)
{
  __shared__ float T[64][129];
  const int tid = threadIdx.x;
  const int bid = blockIdx.x;        // B*KVH*(NL/64) = 512
  const int lt  = bid & 31;
  const int kvh = (bid >> 5) & (NKVH - 1);
  const int b   = bid >> 7;
  const int l0  = lt * 64;

  const float* src = new_cv + (((size_t)(b * NKVH + kvh)) * NL + l0) * ND;
  #pragma unroll
  for (int j = 0; j < 8; ++j) {
    const int i   = tid + j * 256;
    const int row = i >> 5, c4 = i & 31;
    float4 v = *(const float4*)(src + row * ND + c4 * 4);
    T[row][c4 * 4 + 0] = v.x; T[row][c4 * 4 + 1] = v.y;
    T[row][c4 * 4 + 2] = v.z; T[row][c4 * 4 + 3] = v.w;
  }
  __syncthreads();
  bf16_t* dst = vt + ((size_t)(b * NKVH + kvh)) * ND * NL;
  #pragma unroll
  for (int j = 0; j < 4; ++j) {
    const int c = tid + j * 256;
    const int d = c >> 3, l8 = c & 7;
    bf16x8 o;
    #pragma unroll
    for (int e = 0; e < 8; ++e) o[e] = (bf16_t)T[l8 * 8 + e][d];
    *(bf16x8*)(dst + (size_t)d * NL + l0 + l8 * 8) = o;
  }
}

// ---------------------------------------------------------------------------
// Kernel 3: pipelined flash attention, 16x16 swapped MFMA.
// 1024 blocks x 4 waves; wave owns 16 q-rows; KVBLK=32; LDS 32 KB ->
// 4 blocks/CU (launch_bounds(256,4)) = 4 waves/SIMD.
// Schedule (verified in R5): phase t: barrier; STAGE_K(cur,t+2);
// STAGE_V(cur^1,t+1); QKT(t+1 from Kl[cur^1]); SOFTPV(t from Vl[cur]).
// ---------------------------------------------------------------------------
// K tile: 32 rows x 256B (16 chunks of 16B), chunk ^= (row&7).
#define STAGE_K(buf, tt) do {                                                \
    const int l0s = (tt) * KVBLK;                                            \
    _Pragma("unroll")                                                        \
    for (int j = 0; j < 2; ++j) {                                            \
      const int ck = tid + j * 256;                                          \
      const int kr = ck >> 4, kc2 = (ck & 15) ^ (kr & 7);                    \
      gload_lds16(kbb + (size_t)(l0s + kr) * ND + kc2 * 8,                   \
                  &Kl[buf][(wave * 64 + j * 256) * 8]);                      \
    }                                                                        \
  } while (0)

// V^T tile: 128 rows x 64B (4 chunks of 16B), chunk ^= (row&3).
#define STAGE_V(buf, tt) do {                                                \
    const int l0s = (tt) * KVBLK;                                            \
    _Pragma("unroll")                                                        \
    for (int j = 0; j < 2; ++j) {                                            \
      const int ck = tid + j * 256;                                          \
      const int vr = ck >> 2, vc2 = (ck & 3) ^ (vr & 3);                     \
      gload_lds16(vtb + (size_t)vr * NL + (l0s + vc2 * 8),                   \
                  &Vl[buf][(wave * 64 + j * 256) * 8]);                      \
    }                                                                        \
  } while (0)

// S^T(tile) = K.Q from Kl[KBI] into SB[2] (each f32x4).
// A-frag: K[l = lsub*16+llo][k = kc*32+lhi*8+j]; B-frag: qf[kc].
#define QKT(SB, KBI) do {                                                    \
    _Pragma("unroll")                                                        \
    for (int sl = 0; sl < 2; ++sl) {                                         \
      f32x4 acc = (f32x4){0.f, 0.f, 0.f, 0.f};                               \
      _Pragma("unroll")                                                      \
      for (int kc = 0; kc < 4; ++kc) {                                       \
        bf16x8 kf = *(const bf16x8*)                                         \
            &Kl[KBI][((sl * 16 + llo) * 16 + ((kc * 4 + lhi) ^ (llo & 7))) * 8]; \
        acc = __builtin_amdgcn_mfma_f32_16x16x32_bf16(kf, qf[kc], acc, 0, 0, 0); \
      }                                                                      \
      SB[sl] = acc;                                                          \
    }                                                                        \
  } while (0)

// mask + online softmax + PV for tile at L0 using SB[2] and Vl[VBI].
// Lane holds S^T[l = sl*16 + lhi*4 + r][q = llo].
#define SOFTPV(SB, VBI, L0) do {                                             \
    if ((L0) + 31 > s + qw) {                                                \
      const int lim = s + q - (L0);                                          \
      _Pragma("unroll")                                                      \
      for (int sl = 0; sl < 2; ++sl)                                         \
        _Pragma("unroll")                                                    \
        for (int rr = 0; rr < 4; ++rr)                                       \
          if (sl * 16 + lhi * 4 + rr > lim) SB[sl][rr] = -1e30f;             \
    }                                                                        \
    float pm = fmaxf(fmaxf(fmaxf(SB[0][0], SB[0][1]), fmaxf(SB[0][2], SB[0][3])), \
                     fmaxf(fmaxf(SB[1][0], SB[1][1]), fmaxf(SB[1][2], SB[1][3]))); \
    pm = fmaxf(pm, __shfl_xor(pm, 16, 64));                                  \
    pm = fmaxf(pm, __shfl_xor(pm, 32, 64));                                  \
    if (!__all(pm - mreg <= 8.f)) {                                          \
      const float mnew  = fmaxf(mreg, pm);                                   \
      const float alpha = exp2f(mreg - mnew);                                \
      mreg = mnew;                                                           \
      lreg *= alpha;                                                         \
      _Pragma("unroll")                                                      \
      for (int i = 0; i < 8; ++i) oacc[i] *= alpha;                          \
    }                                                                        \
    const float p0 = exp2f(SB[0][0] - mreg), p1 = exp2f(SB[0][1] - mreg);    \
    const float p2 = exp2f(SB[0][2] - mreg), p3 = exp2f(SB[0][3] - mreg);    \
    const float p4 = exp2f(SB[1][0] - mreg), p5 = exp2f(SB[1][1] - mreg);    \
    const float p6 = exp2f(SB[1][2] - mreg), p7 = exp2f(SB[1][3] - mreg);    \
    float ts = ((p0 + p1) + (p2 + p3)) + ((p4 + p5) + (p6 + p7));            \
    ts += __shfl_xor(ts, 16, 64);                                            \
    ts += __shfl_xor(ts, 32, 64);                                            \
    lreg += ts;                                                              \
    const u32 pk00 = pack_bf16(p0, p1), pk01 = pack_bf16(p2, p3);            \
    const u32 pk10 = pack_bf16(p4, p5), pk11 = pack_bf16(p6, p7);            \
    const int src0 = ((lhi & 1) << 5) + llo;                                 \
    const int src1 = src0 + 16;                                              \
    const u32 a00 = (u32)__shfl((int)pk00, src0, 64);                        \
    const u32 a01 = (u32)__shfl((int)pk01, src0, 64);                        \
    const u32 a02 = (u32)__shfl((int)pk00, src1, 64);                        \
    const u32 a03 = (u32)__shfl((int)pk01, src1, 64);                        \
    const u32 a10 = (u32)__shfl((int)pk10, src0, 64);                        \
    const u32 a11 = (u32)__shfl((int)pk11, src0, 64);                        \
    const u32 a12 = (u32)__shfl((int)pk10, src1, 64);                        \
    const u32 a13 = (u32)__shfl((int)pk11, src1, 64);                        \
    union { u32 w[4]; bf16x8 v; } uu;                                        \
    uu.w[0] = (lhi < 2) ? a00 : a10;                                         \
    uu.w[1] = (lhi < 2) ? a01 : a11;                                         \
    uu.w[2] = (lhi < 2) ? a02 : a12;                                         \
    uu.w[3] = (lhi < 2) ? a03 : a13;                                         \
    _Pragma("unroll")                                                        \
    for (int dsb = 0; dsb < 8; ++dsb) {                                      \
      bf16x8 va = *(const bf16x8*)                                           \
          &Vl[VBI][((dsb * 16 + llo) * 4 + (lhi ^ (llo & 3))) * 8];          \
      oacc[dsb] = __builtin_amdgcn_mfma_f32_16x16x32_bf16(va, uu.v, oacc[dsb], 0, 0, 0); \
    }                                                                        \
  } while (0)

__global__ __launch_bounds__(256, 4) void attn_kernel(
    const float* __restrict__ qin, const bf16_t* __restrict__ kb,
    const bf16_t* __restrict__ vt, const int* __restrict__ seq_lens,
    float* __restrict__ out)
{
  __shared__ bf16_t Kl[2][KVBLK * ND];   // 16 KB (rows of 256B, chunk^=(row&7))
  __shared__ bf16_t Vl[2][ND * KVBLK];   // 16 KB (rows of 64B,  chunk^=(row&3))

  const int tid  = threadIdx.x;
  const int wave = tid >> 6, lane = tid & 63;
  const int llo  = lane & 15;            // q column
  const int lhi  = lane >> 4;            // 0..3

  // bid: b major -> 64 consecutive bids share (b,kvh) K/V panel (L2 reuse).
  const int bid = blockIdx.x;            // 1024
  const int b   = bid >> 8;
  const int r   = bid & 255;
  const int h   = r >> 4;
  const int qt  = r & 15;
  const int kvh = h >> 2;
  const int s   = seq_lens[b];
  const int qw  = qt * 64 + wave * 16;   // wave's q base (16 rows)
  const int q   = qw + llo;

  const bf16_t* kbb = kb + ((size_t)(b * NKVH + kvh)) * NL * ND;
  const bf16_t* vtb = vt + ((size_t)(b * NKVH + kvh)) * ND * NL;

  // Q fragments (B operand): qf[kc][j] = Q[q][kc*32 + lhi*8 + j]
  bf16x8 qf[4];
  {
    const float* qb = qin + ((size_t)((b * NQL + q) * NH + h)) * ND;
    #pragma unroll
    for (int kc = 0; kc < 4; ++kc) {
      float4 x0 = *(const float4*)(qb + kc * 32 + lhi * 8);
      float4 x1 = *(const float4*)(qb + kc * 32 + lhi * 8 + 4);
      bf16x8 f;
      f[0] = (bf16_t)(x0.x * QSCALE_LOG2E); f[1] = (bf16_t)(x0.y * QSCALE_LOG2E);
      f[2] = (bf16_t)(x0.z * QSCALE_LOG2E); f[3] = (bf16_t)(x0.w * QSCALE_LOG2E);
      f[4] = (bf16_t)(x1.x * QSCALE_LOG2E); f[5] = (bf16_t)(x1.y * QSCALE_LOG2E);
      f[6] = (bf16_t)(x1.z * QSCALE_LOG2E); f[7] = (bf16_t)(x1.w * QSCALE_LOG2E);
      qf[kc] = f;
    }
  }

  f32x4 oacc[8];   // O^T[d = dsb*16 + lhi*4 + r][q = llo]
  #pragma unroll
  for (int i = 0; i < 8; ++i) oacc[i] = (f32x4){0.f, 0.f, 0.f, 0.f};
  float mreg = -1e30f, lreg = 0.f;

  const int ntiles = (s + qt * 64 + 64 + KVBLK - 1) / KVBLK;  // >= 2 always

  // ---- prologue: stage K0, V0, K1; compute QK(0) ----
  STAGE_K(0, 0);
  STAGE_V(0, 0);
  STAGE_K(1, 1);
  __syncthreads();

  f32x4 sA[2], sB[2];
  QKT(sA, 0);

  // ---- main loop, 2 phases per trip, all buffer indices static ----
  for (int t = 0; ; t += 2) {
    // --- phase t (cur=0): tile t uses Kl[0]/Vl[0] ---
    __syncthreads();                       // drains K(t+1)->Kl[1], V(t)->Vl[0]
    if (t + 2 < ntiles) STAGE_K(0, t + 2); // Kl[0] last read phase t-1 (QKT)
    if (t + 1 < ntiles) STAGE_V(1, t + 1); // Vl[1] last read phase t-1 (PV)
    const bool gB = (t + 1 < ntiles) && ((t + 1) * KVBLK <= s + qw + 15);
    if (gB) QKT(sB, 1);
    if (t * KVBLK <= s + qw + 15) SOFTPV(sA, 0, t * KVBLK);
    if (t + 1 >= ntiles) break;

    // --- phase t+1 (cur=1): tile t+1 uses Kl[1]/Vl[1] ---
    __syncthreads();                       // drains K(t+2)->Kl[0], V(t+1)->Vl[1]
    if (t + 3 < ntiles) STAGE_K(1, t + 3); // Kl[1] last read phase t (QKT)
    if (t + 2 < ntiles) STAGE_V(0, t + 2); // Vl[0] last read phase t (PV)
    const bool gA = (t + 2 < ntiles) && ((t + 2) * KVBLK <= s + qw + 15);
    if (gA) QKT(sA, 0);
    if ((t + 1) * KVBLK <= s + qw + 15) SOFTPV(sB, 1, (t + 1) * KVBLK);
    if (t + 2 >= ntiles) break;
  }

  // ---- epilogue: normalize, store O; lane holds d = dsb*16 + lhi*4 + r ----
  const float linv = 1.0f / lreg;
  float* ob = out + ((size_t)((b * NQL + q) * NH + h)) * ND;
  #pragma unroll
  for (int dsb = 0; dsb < 8; ++dsb) {
    float4 v;
    v.x = oacc[dsb][0] * linv;
    v.y = oacc[dsb][1] * linv;
    v.z = oacc[dsb][2] * linv;
    v.w = oacc[dsb][3] * linv;
    *(float4*)(ob + dsb * 16 + lhi * 4) = v;
  }
}

// ---------------------------------------------------------------------------
extern "C" void kernel_launch(void* const* d_in, const int* in_sizes, int n_in,
                              void* d_out, int out_size, void* d_ws, size_t ws_size,
                              hipStream_t stream)
{
  const float* q        = (const float*)d_in[0];
  const float* k        = (const float*)d_in[1];
  const float* v        = (const float*)d_in[2];
  const float* cache_k  = (const float*)d_in[3];
  const float* cache_v  = (const float*)d_in[4];
  const int*   seq_lens = (const int*)d_in[5];

  float* out    = (float*)d_out;
  float* new_ck = out + (size_t)NB * NQL * NH * ND;
  float* new_cv = new_ck + (size_t)NB * NKVH * NL * ND;

  bf16_t* kb = (bf16_t*)d_ws;                                 // 8 MB bf16 K
  bf16_t* vt = kb + (size_t)NB * NKVH * NL * ND;              // 8 MB bf16 V^T

  hipLaunchKernelGGL(update_cache_kernel, dim3(2048), dim3(256), 0, stream,
                     k, v, cache_k, cache_v, seq_lens, new_ck, new_cv, kb);
  hipLaunchKernelGGL(transpose_v_kernel, dim3(NB * NKVH * (NL / 64)), dim3(256), 0, stream,
                     new_cv, vt);
  hipLaunchKernelGGL(attn_kernel, dim3(NB * NH * (NQL / 64)), dim3(256), 0, stream,
                     q, kb, vt, seq_lens, out);
}